// Round 3
// baseline (785.609 us; speedup 1.0000x reference)
//
#include <hip/hip_runtime.h>
#include <hip/hip_bf16.h>
#include <hip/hip_cooperative_groups.h>

namespace cg = cooperative_groups;

#define NN 8192
#define CIN 32
#define COUT 64
#define KF 5
#define SPLITS 8
#define NVB 1024   // virtual blocks: 128 i-tiles x 8 K-slices

typedef __attribute__((ext_vector_type(8))) short bf16x8_t;
typedef __attribute__((ext_vector_type(4))) float f32x4_t;

// fp32 -> bf16 RNE
__device__ __forceinline__ short f2bf(float f) {
    unsigned u = __builtin_bit_cast(unsigned, f);
    unsigned r = (u + 0x7FFFu + ((u >> 16) & 1u)) >> 16;
    return (short)(unsigned short)r;
}

__device__ __forceinline__ bf16x8_t cvt8(float4 a, float4 b) {
    bf16x8_t v;
    v[0] = f2bf(a.x); v[1] = f2bf(a.y); v[2] = f2bf(a.z); v[3] = f2bf(a.w);
    v[4] = f2bf(b.x); v[5] = f2bf(b.y); v[6] = f2bf(b.z); v[7] = f2bf(b.w);
    return v;
}

// D layout (m89): col = lane&15 -> i, row = (lane>>4)*4 + reg -> c
__device__ __forceinline__ void store_part(float* part, int s, int i0, int r, int g,
                                           const f32x4_t& acc0, const f32x4_t& acc1) {
    float* pbase = part + (size_t)s * CIN * NN + i0 + r;
#pragma unroll
    for (int t = 0; t < 4; ++t) {
        pbase[(size_t)(g * 4 + t) * NN]      = acc0[t];
        pbase[(size_t)(g * 4 + t + 16) * NN] = acc1[t];
    }
}

// GEMM pass over bf16 L: part[s][c][i] = sum_j Tc[c][j]*Lb[i][j]
__device__ __forceinline__ void pass_bf(int blockId, int nb, int wave, int g, int r,
                                        const short* __restrict__ Lb,
                                        const short* __restrict__ Tc,
                                        float* __restrict__ part) {
    for (int vb = blockId; vb < NVB; vb += nb) {
        const int bx = vb & 127, s = vb >> 7;
        const int i0 = bx * 64 + wave * 16;
        const int jb = s * (NN / SPLITS);
        const short* Lrow = Lb + (size_t)(i0 + r) * NN;
        f32x4_t acc0 = {0.f, 0.f, 0.f, 0.f};
        f32x4_t acc1 = {0.f, 0.f, 0.f, 0.f};
        for (int j = jb; j < jb + NN / SPLITS; j += 32) {
            const int jl = j + g * 8;
            bf16x8_t bfr = *reinterpret_cast<const bf16x8_t*>(Lrow + jl);
            bf16x8_t a0  = *reinterpret_cast<const bf16x8_t*>(Tc + (size_t)r * NN + jl);
            bf16x8_t a1  = *reinterpret_cast<const bf16x8_t*>(Tc + (size_t)(r + 16) * NN + jl);
            acc0 = __builtin_amdgcn_mfma_f32_16x16x32_bf16(a0, bfr, acc0, 0, 0, 0);
            acc1 = __builtin_amdgcn_mfma_f32_16x16x32_bf16(a1, bfr, acc1, 0, 0, 0);
        }
        store_part(part, s, i0, r, g, acc0, acc1);
    }
}

// T_next = alpha*sum_s part[s] - Tprev; write fp32 Tf + bf16 Tb
__device__ __forceinline__ void combine_body(long gtid, long gthreads,
                                             const float* __restrict__ part,
                                             const float* __restrict__ Tprev,
                                             float alpha, int has_prev,
                                             float* __restrict__ Tf,
                                             short* __restrict__ Tb) {
    const long NQ = CIN * NN / 4;
    for (long idx = gtid; idx < NQ; idx += gthreads) {
        const float4* p = reinterpret_cast<const float4*>(part);
        float4 sv = p[idx];
#pragma unroll
        for (int t = 1; t < SPLITS; ++t) {
            float4 v = p[(size_t)t * NQ + idx];
            sv.x += v.x; sv.y += v.y; sv.z += v.z; sv.w += v.w;
        }
        sv.x *= alpha; sv.y *= alpha; sv.z *= alpha; sv.w *= alpha;
        if (has_prev) {
            float4 pv = reinterpret_cast<const float4*>(Tprev)[idx];
            sv.x -= pv.x; sv.y -= pv.y; sv.z -= pv.z; sv.w -= pv.w;
        }
        reinterpret_cast<float4*>(Tf)[idx] = sv;
        short4 b;
        b.x = f2bf(sv.x); b.y = f2bf(sv.y); b.z = f2bf(sv.z); b.w = f2bf(sv.w);
        reinterpret_cast<short4*>(Tb)[idx] = b;
    }
}

__global__ __launch_bounds__(256, 4) void cheb_mono(
    const float* __restrict__ L, const float* __restrict__ x,
    const float* __restrict__ theta, const float* __restrict__ bias,
    float* __restrict__ y,
    short* __restrict__ Lb, float* __restrict__ part,
    float* __restrict__ Tf1, float* __restrict__ Tf2,
    float* __restrict__ Tf3, float* __restrict__ Tf4,
    short* __restrict__ Tb)
{
    cg::grid_group grid = cg::this_grid();
    const int lane = threadIdx.x & 63;
    const int wave = threadIdx.x >> 6;
    const int g = lane >> 4;
    const int r = lane & 15;
    const int nb = gridDim.x;
    const long gtid = (long)blockIdx.x * 256 + threadIdx.x;
    const long gthreads = (long)nb * 256;

    // ---- Pass 1: part = x @ L^T (fp32 L read, inline bf16 cvt, stash Lb)
    for (int vb = blockIdx.x; vb < NVB; vb += nb) {
        const int bx = vb & 127, s = vb >> 7;
        const int i0 = bx * 64 + wave * 16;
        const int jb = s * (NN / SPLITS);
        const float* Lrow = L + (size_t)(i0 + r) * NN;
        short* LbRow = Lb + (size_t)(i0 + r) * NN;
        f32x4_t acc0 = {0.f, 0.f, 0.f, 0.f};
        f32x4_t acc1 = {0.f, 0.f, 0.f, 0.f};
        for (int j = jb; j < jb + NN / SPLITS; j += 32) {
            const int jl = j + g * 8;
            float4 l0 = *reinterpret_cast<const float4*>(Lrow + jl);
            float4 l1 = *reinterpret_cast<const float4*>(Lrow + jl + 4);
            bf16x8_t bfr = cvt8(l0, l1);
            *reinterpret_cast<bf16x8_t*>(LbRow + jl) = bfr;  // disjoint tiles
            float4 a00 = *reinterpret_cast<const float4*>(x + (size_t)r * NN + jl);
            float4 a01 = *reinterpret_cast<const float4*>(x + (size_t)r * NN + jl + 4);
            float4 a10 = *reinterpret_cast<const float4*>(x + (size_t)(r + 16) * NN + jl);
            float4 a11 = *reinterpret_cast<const float4*>(x + (size_t)(r + 16) * NN + jl + 4);
            acc0 = __builtin_amdgcn_mfma_f32_16x16x32_bf16(cvt8(a00, a01), bfr, acc0, 0, 0, 0);
            acc1 = __builtin_amdgcn_mfma_f32_16x16x32_bf16(cvt8(a10, a11), bfr, acc1, 0, 0, 0);
        }
        store_part(part, s, i0, r, g, acc0, acc1);
    }
    grid.sync();
    combine_body(gtid, gthreads, part, nullptr, 1.0f, 0, Tf1, Tb);   // T1
    grid.sync();
    pass_bf(blockIdx.x, nb, wave, g, r, Lb, Tb, part);               // T1 @ L^T
    grid.sync();
    combine_body(gtid, gthreads, part, x, 2.0f, 1, Tf2, Tb);         // T2
    grid.sync();
    pass_bf(blockIdx.x, nb, wave, g, r, Lb, Tb, part);               // T2 @ L^T
    grid.sync();
    combine_body(gtid, gthreads, part, Tf1, 2.0f, 1, Tf3, Tb);       // T3
    grid.sync();
    pass_bf(blockIdx.x, nb, wave, g, r, Lb, Tb, part);               // T3 @ L^T
    grid.sync();
    combine_body(gtid, gthreads, part, Tf2, 2.0f, 1, Tf4, Tb);       // T4
    grid.sync();

    // ---- Final einsum: y[o][i] = bias[o] + sum_{c,k} T_k[c][i]*theta[o][c][k]
    const long NW = (long)(COUT / 2) * NN;  // 2 outputs per work item
    for (long t = gtid; t < NW; t += gthreads) {
        const int i = (int)(t & (NN - 1));
        const int op = (int)(t >> 13);
        const int o0 = op * 2, o1 = op * 2 + 1;
        float a0 = bias[o0], a1 = bias[o1];
        for (int c = 0; c < CIN; ++c) {
            size_t off = (size_t)c * NN + i;
            float t0 = x[off], t1 = Tf1[off], t2 = Tf2[off], t3 = Tf3[off], t4 = Tf4[off];
            const float* th0 = theta + ((size_t)o0 * CIN + c) * KF;
            const float* th1 = theta + ((size_t)o1 * CIN + c) * KF;
            a0 += t0 * th0[0] + t1 * th0[1] + t2 * th0[2] + t3 * th0[3] + t4 * th0[4];
            a1 += t0 * th1[0] + t1 * th1[1] + t2 * th1[2] + t3 * th1[3] + t4 * th1[4];
        }
        y[(size_t)o0 * NN + i] = a0;
        y[(size_t)o1 * NN + i] = a1;
    }
}

// ---------------- fallback multi-kernel path (if cooperative launch fails) ----------------

__global__ void cvt_kernel(const float* __restrict__ src, short* __restrict__ dst, long n4) {
    long stride = (long)gridDim.x * blockDim.x;
    for (long idx = blockIdx.x * (long)blockDim.x + threadIdx.x; idx < n4; idx += stride) {
        float4 v = reinterpret_cast<const float4*>(src)[idx];
        short4 b;
        b.x = f2bf(v.x); b.y = f2bf(v.y); b.z = f2bf(v.z); b.w = f2bf(v.w);
        reinterpret_cast<short4*>(dst)[idx] = b;
    }
}

__global__ __launch_bounds__(256, 4) void cheb_pass_bf_kernel(
    const short* __restrict__ Lb, const short* __restrict__ Tcur, float* __restrict__ part) {
    const int lane = threadIdx.x & 63, wave = threadIdx.x >> 6;
    const int g = lane >> 4, r = lane & 15;
    pass_bf(blockIdx.x + blockIdx.y * gridDim.x, gridDim.x * gridDim.y, wave, g, r, Lb, Tcur, part);
}

__global__ void combine_kernel(const float* __restrict__ part, const float* __restrict__ Tprev,
                               const float alpha, const int has_prev,
                               float* __restrict__ Tf, short* __restrict__ Tb) {
    combine_body((long)blockIdx.x * blockDim.x + threadIdx.x,
                 (long)gridDim.x * blockDim.x, part, Tprev, alpha, has_prev, Tf, Tb);
}

__global__ __launch_bounds__(256) void final_kernel(
    const float* __restrict__ x, const float* __restrict__ T1, const float* __restrict__ T2,
    const float* __restrict__ T3, const float* __restrict__ T4,
    const float* __restrict__ theta, const float* __restrict__ bias, float* __restrict__ y) {
    const long gtid = (long)blockIdx.x * blockDim.x + threadIdx.x;
    const long gthreads = (long)gridDim.x * blockDim.x;
    const long NW = (long)(COUT / 2) * NN;
    for (long t = gtid; t < NW; t += gthreads) {
        const int i = (int)(t & (NN - 1));
        const int op = (int)(t >> 13);
        const int o0 = op * 2, o1 = op * 2 + 1;
        float a0 = bias[o0], a1 = bias[o1];
        for (int c = 0; c < CIN; ++c) {
            size_t off = (size_t)c * NN + i;
            float t0 = x[off], t1 = T1[off], t2 = T2[off], t3 = T3[off], t4 = T4[off];
            const float* th0 = theta + ((size_t)o0 * CIN + c) * KF;
            const float* th1 = theta + ((size_t)o1 * CIN + c) * KF;
            a0 += t0 * th0[0] + t1 * th0[1] + t2 * th0[2] + t3 * th0[3] + t4 * th0[4];
            a1 += t0 * th1[0] + t1 * th1[1] + t2 * th1[2] + t3 * th1[3] + t4 * th1[4];
        }
        y[(size_t)o0 * NN + i] = a0;
        y[(size_t)o1 * NN + i] = a1;
    }
}

extern "C" void kernel_launch(void* const* d_in, const int* in_sizes, int n_in,
                              void* d_out, int out_size, void* d_ws, size_t ws_size,
                              hipStream_t stream) {
    const float* L     = (const float*)d_in[0];
    const float* x     = (const float*)d_in[1];
    const float* theta = (const float*)d_in[2];
    const float* bias  = (const float*)d_in[3];
    float* y = (float*)d_out;

    const size_t TE = (size_t)CIN * NN;
    const size_t LE = (size_t)NN * NN;

    // ws layout: Lb(128MB) | part(8MB) | Tf1..Tf4(1MB ea) | Tb(0.5MB)
    short* Lb   = (short*)d_ws;
    float* part = (float*)(Lb + LE);
    float* Tf1 = part + (size_t)SPLITS * TE;
    float* Tf2 = Tf1 + TE;
    float* Tf3 = Tf2 + TE;
    float* Tf4 = Tf3 + TE;
    short* Tb  = (short*)(Tf4 + TE);

    int maxb = 0;
    hipError_t occ_err = hipOccupancyMaxActiveBlocksPerMultiprocessor(
        &maxb, reinterpret_cast<const void*>(cheb_mono), 256, 0);
    int nblk = (occ_err == hipSuccess && maxb > 0) ? maxb * 256 : 0;  // 256 CUs (MI355X)
    if (nblk > NVB) nblk = NVB;

    hipError_t lerr = hipErrorUnknown;
    if (nblk > 0) {
        void* args[] = {(void*)&L, (void*)&x, (void*)&theta, (void*)&bias, (void*)&y,
                        (void*)&Lb, (void*)&part, (void*)&Tf1, (void*)&Tf2, (void*)&Tf3,
                        (void*)&Tf4, (void*)&Tb};
        lerr = hipLaunchCooperativeKernel(reinterpret_cast<const void*>(cheb_mono),
                                          dim3(nblk), dim3(256), args, 0, stream);
    }
    if (lerr != hipSuccess) {
        // Fallback: R2's proven multi-kernel path
        const dim3 passGrid(NN / 64, SPLITS);
        const int cmbBlocks = (int)((TE / 4 + 255) / 256);
        cvt_kernel<<<(int)(TE / 4 / 256), 256, 0, stream>>>(x, Tb, (long)(TE / 4));
        cvt_kernel<<<2048, 256, 0, stream>>>(L, Lb, (long)(LE / 4));
        cheb_pass_bf_kernel<<<passGrid, 256, 0, stream>>>(Lb, Tb, part);
        combine_kernel<<<cmbBlocks, 256, 0, stream>>>(part, nullptr, 1.0f, 0, Tf1, Tb);
        cheb_pass_bf_kernel<<<passGrid, 256, 0, stream>>>(Lb, Tb, part);
        combine_kernel<<<cmbBlocks, 256, 0, stream>>>(part, x, 2.0f, 1, Tf2, Tb);
        cheb_pass_bf_kernel<<<passGrid, 256, 0, stream>>>(Lb, Tb, part);
        combine_kernel<<<cmbBlocks, 256, 0, stream>>>(part, Tf1, 2.0f, 1, Tf3, Tb);
        cheb_pass_bf_kernel<<<passGrid, 256, 0, stream>>>(Lb, Tb, part);
        combine_kernel<<<cmbBlocks, 256, 0, stream>>>(part, Tf2, 2.0f, 1, Tf4, Tb);
        final_kernel<<<512, 256, 0, stream>>>(x, Tf1, Tf2, Tf3, Tf4, theta, bias, y);
    }
}

// Round 4
// 265.076 us; speedup vs baseline: 2.9637x; 2.9637x over previous
//
#include <hip/hip_runtime.h>

#define NN 8192
#define CIN 32
#define COUT 64
#define KF 5

typedef __attribute__((ext_vector_type(8))) short bf16x8_t;
typedef __attribute__((ext_vector_type(4))) float f32x4_t;

// fp32 -> bf16 RNE
__device__ __forceinline__ short f2bf(float f) {
    unsigned u = __builtin_bit_cast(unsigned, f);
    unsigned r = (u + 0x7FFFu + ((u >> 16) & 1u)) >> 16;
    return (short)(unsigned short)r;
}

__device__ __forceinline__ bf16x8_t cvt8(float4 a, float4 b) {
    bf16x8_t v;
    v[0] = f2bf(a.x); v[1] = f2bf(a.y); v[2] = f2bf(a.z); v[3] = f2bf(a.w);
    v[4] = f2bf(b.x); v[5] = f2bf(b.y); v[6] = f2bf(b.z); v[7] = f2bf(b.w);
    return v;
}

// x fp32 -> bf16 (exactly CIN*NN/4 = 65536 quads; grid 256x256)
__global__ void cvt_kernel(const float* __restrict__ src, short* __restrict__ dst) {
    int idx = blockIdx.x * 256 + threadIdx.x;
    float4 v = reinterpret_cast<const float4*>(src)[idx];
    short4 o;
    o.x = f2bf(v.x); o.y = f2bf(v.y); o.z = f2bf(v.z); o.w = f2bf(v.w);
    reinterpret_cast<short4*>(dst)[idx] = o;
}

// Store one wave's MFMA partials to LDS.
// D layout (m89, R1-validated): col=lane&15 -> i, row=(lane>>4)*4+reg -> c
__device__ __forceinline__ void stash_partials(float* red, int wave, int g, int r,
                                               const f32x4_t& acc0, const f32x4_t& acc1) {
    const int base = wave * 512 + g * 64 + r;   // red[wave][c][i], c=g*4+t, i=r
#pragma unroll
    for (int t = 0; t < 4; ++t) {
        red[base + t * 16]       = acc0[t];
        red[base + t * 16 + 256] = acc1[t];     // c+16
    }
}

// Reduce 8 wave partials; T = alpha*sum - Tprev; write fp32 Tf + bf16 Tb.
__device__ __forceinline__ void reduce_write(const float* red, int tid, int i0,
                                             float alpha, const float* __restrict__ Tprev,
                                             float* __restrict__ Tf, short* __restrict__ Tb) {
    __syncthreads();
    const int c = tid >> 4, il = tid & 15;
    float s = red[tid];
#pragma unroll
    for (int w = 1; w < 8; ++w) s += red[w * 512 + tid];
    float val = alpha * s;
    const size_t off = (size_t)c * NN + i0 + il;
    if (Tprev) val -= Tprev[off];
    Tf[off] = val;
    Tb[off] = f2bf(val);
}

// MFMA over one wave's K-range using bf16 L and bf16 A
__device__ __forceinline__ void mfma_range(const short* __restrict__ Lb,
                                           const short* __restrict__ A,
                                           int i0, int r, int g, int jb,
                                           f32x4_t& acc0, f32x4_t& acc1) {
    const short* Lrow = Lb + (size_t)(i0 + r) * NN;
    for (int j = jb; j < jb + NN / 8; j += 32) {
        const int jl = j + g * 8;
        bf16x8_t b  = *reinterpret_cast<const bf16x8_t*>(Lrow + jl);
        bf16x8_t a0 = *reinterpret_cast<const bf16x8_t*>(A + (size_t)r * NN + jl);
        bf16x8_t a1 = *reinterpret_cast<const bf16x8_t*>(A + (size_t)(r + 16) * NN + jl);
        acc0 = __builtin_amdgcn_mfma_f32_16x16x32_bf16(a0, b, acc0, 0, 0, 0);
        acc1 = __builtin_amdgcn_mfma_f32_16x16x32_bf16(a1, b, acc1, 0, 0, 0);
    }
}

// Pass 1: reads fp32 L (converting + stashing bf16 Lb), A = Tb0; T1 = acc.
// Block: 512 thr = 8 waves; i-tile 16 (i0 = blockIdx.x*16); wave w owns K-range [w*1024,(w+1)*1024)
__global__ __launch_bounds__(512, 4) void pass1_kernel(
    const float* __restrict__ L, const short* __restrict__ Tb0,
    short* __restrict__ Lb, float* __restrict__ Tf1, short* __restrict__ Tb1)
{
    __shared__ float red[8 * 512];
    const int tid = threadIdx.x, wave = tid >> 6, lane = tid & 63;
    const int g = lane >> 4, r = lane & 15;
    const int i0 = blockIdx.x * 16;
    const int jb = wave * (NN / 8);

    const float* Lrow = L + (size_t)(i0 + r) * NN;
    short* LbRow = Lb + (size_t)(i0 + r) * NN;
    f32x4_t acc0 = {0.f, 0.f, 0.f, 0.f};
    f32x4_t acc1 = {0.f, 0.f, 0.f, 0.f};
    for (int j = jb; j < jb + NN / 8; j += 32) {
        const int jl = j + g * 8;
        float4 l0 = *reinterpret_cast<const float4*>(Lrow + jl);
        float4 l1 = *reinterpret_cast<const float4*>(Lrow + jl + 4);
        bf16x8_t b = cvt8(l0, l1);
        *reinterpret_cast<bf16x8_t*>(LbRow + jl) = b;   // disjoint rows per block
        bf16x8_t a0 = *reinterpret_cast<const bf16x8_t*>(Tb0 + (size_t)r * NN + jl);
        bf16x8_t a1 = *reinterpret_cast<const bf16x8_t*>(Tb0 + (size_t)(r + 16) * NN + jl);
        acc0 = __builtin_amdgcn_mfma_f32_16x16x32_bf16(a0, b, acc0, 0, 0, 0);
        acc1 = __builtin_amdgcn_mfma_f32_16x16x32_bf16(a1, b, acc1, 0, 0, 0);
    }
    stash_partials(red, wave, g, r, acc0, acc1);
    reduce_write(red, tid, i0, 1.0f, nullptr, Tf1, Tb1);
}

// Middle passes (2,3): T_next = 2*(Tcur @ L^T) - Tprev
__global__ __launch_bounds__(512, 4) void passmid_kernel(
    const short* __restrict__ Lb, const short* __restrict__ Tbin,
    const float* __restrict__ Tprev, float* __restrict__ Tf, short* __restrict__ Tb)
{
    __shared__ float red[8 * 512];
    const int tid = threadIdx.x, wave = tid >> 6, lane = tid & 63;
    const int g = lane >> 4, r = lane & 15;
    const int i0 = blockIdx.x * 16;
    f32x4_t acc0 = {0.f, 0.f, 0.f, 0.f};
    f32x4_t acc1 = {0.f, 0.f, 0.f, 0.f};
    mfma_range(Lb, Tbin, i0, r, g, wave * (NN / 8), acc0, acc1);
    stash_partials(red, wave, g, r, acc0, acc1);
    reduce_write(red, tid, i0, 2.0f, Tprev, Tf, Tb);
}

// Pass 4 + fused final einsum:
//   T4 = 2*(T3 @ L^T) - T2 (kept in LDS only)
//   y[o][i] = bias[o] + sum_{c,k} T_k[c][i] * theta[o][c][k]
__global__ __launch_bounds__(512, 4) void pass4_kernel(
    const short* __restrict__ Lb, const short* __restrict__ Tb3,
    const float* __restrict__ Tf2, const float* __restrict__ x,
    const float* __restrict__ Tf1, const float* __restrict__ Tf3,
    const float* __restrict__ theta, const float* __restrict__ bias,
    float* __restrict__ y)
{
    __shared__ float red[8 * 512];              // 16 KB: partials, then T4[c][i]
    __shared__ float thS[COUT * CIN * KF];      // 40 KB
    const int tid = threadIdx.x, wave = tid >> 6, lane = tid & 63;
    const int g = lane >> 4, r = lane & 15;
    const int i0 = blockIdx.x * 16;
    f32x4_t acc0 = {0.f, 0.f, 0.f, 0.f};
    f32x4_t acc1 = {0.f, 0.f, 0.f, 0.f};
    mfma_range(Lb, Tb3, i0, r, g, wave * (NN / 8), acc0, acc1);
    stash_partials(red, wave, g, r, acc0, acc1);
    __syncthreads();

    // reduce column tid -> T4, overwrite red[tid] (column-exclusive, safe pre-barrier)
    {
        const int c = tid >> 4, il = tid & 15;
        float s = red[tid];
#pragma unroll
        for (int w = 1; w < 8; ++w) s += red[w * 512 + tid];
        red[tid] = 2.0f * s - Tf2[(size_t)c * NN + i0 + il];
    }
    // stage theta
    for (int t = tid; t < COUT * CIN * KF; t += 512) thS[t] = theta[t];
    __syncthreads();

    // final: thread -> (o0 = tid>>4, o0+32) x column (i0 + (tid&15))
    const int o0 = tid >> 4, il = tid & 15;
    float a0 = bias[o0], a1 = bias[o0 + 32];
    for (int c = 0; c < CIN; ++c) {
        const size_t off = (size_t)c * NN + i0 + il;
        const float t0 = x[off], t1 = Tf1[off], t2 = Tf2[off], t3 = Tf3[off];
        const float t4 = red[c * 16 + il];
        const float* th0 = &thS[(o0 * CIN + c) * KF];
        const float* th1 = &thS[((o0 + 32) * CIN + c) * KF];
        a0 += t0 * th0[0] + t1 * th0[1] + t2 * th0[2] + t3 * th0[3] + t4 * th0[4];
        a1 += t0 * th1[0] + t1 * th1[1] + t2 * th1[2] + t3 * th1[3] + t4 * th1[4];
    }
    y[(size_t)o0 * NN + i0 + il]        = a0;
    y[(size_t)(o0 + 32) * NN + i0 + il] = a1;
}

extern "C" void kernel_launch(void* const* d_in, const int* in_sizes, int n_in,
                              void* d_out, int out_size, void* d_ws, size_t ws_size,
                              hipStream_t stream) {
    const float* L     = (const float*)d_in[0];
    const float* x     = (const float*)d_in[1];
    const float* theta = (const float*)d_in[2];
    const float* bias  = (const float*)d_in[3];
    float* y = (float*)d_out;

    const size_t TE = (size_t)CIN * NN;
    const size_t LE = (size_t)NN * NN;

    // ws: Lb(128MB) | Tf1,Tf2,Tf3 (1MB ea fp32) | Tb0..Tb3 (0.5MB ea bf16)
    short* Lb  = (short*)d_ws;
    float* Tf1 = (float*)(Lb + LE);
    float* Tf2 = Tf1 + TE;
    float* Tf3 = Tf2 + TE;
    short* Tb0 = (short*)(Tf3 + TE);
    short* Tb1 = Tb0 + TE;
    short* Tb2 = Tb1 + TE;
    short* Tb3 = Tb2 + TE;

    cvt_kernel<<<256, 256, 0, stream>>>(x, Tb0);
    pass1_kernel<<<NN / 16, 512, 0, stream>>>(L, Tb0, Lb, Tf1, Tb1);
    passmid_kernel<<<NN / 16, 512, 0, stream>>>(Lb, Tb1, x,   Tf2, Tb2);   // T2 = 2*T1@L^T - T0
    passmid_kernel<<<NN / 16, 512, 0, stream>>>(Lb, Tb2, Tf1, Tf3, Tb3);   // T3
    pass4_kernel<<<NN / 16, 512, 0, stream>>>(Lb, Tb3, Tf2, x, Tf1, Tf3, theta, bias, y);
}